// Round 2
// baseline (380.035 us; speedup 1.0000x reference)
//
#include <hip/hip_runtime.h>

// PhysicsRouter: N=B*T rows, C channels, E=4 experts, TOP_K=2, all fp32.
// Outputs concatenated in d_out (float):
//   [0, N*4)                logits
//   [N*4, N*4+N*2)          top_k_indices (as float)
//   [N*6, N*6+1)            aux_loss
//   [N*6+1, N*6+1+N*2)      top_k_weights

#define NEXP 4
#define ROWS_PER_WAVE 4

__global__ __launch_bounds__(256) void physics_router_main(
    const float* __restrict__ hidden,   // [N, C]
    const float* __restrict__ mass,     // [N]
    const float* __restrict__ gate,     // [E, C]
    const float* __restrict__ bias,     // [E]
    float* __restrict__ out_logits,     // [N*4]
    float* __restrict__ out_idx,        // [N*2] (float-encoded ints)
    float* __restrict__ out_w,          // [N*2]
    float* __restrict__ ws_sums,        // [4] global expert-importance accum
    int C)
{
    __shared__ float lds_sum[NEXP];
    const int tid = threadIdx.x;
    if (tid < NEXP) lds_sum[tid] = 0.f;
    __syncthreads();

    const int lane = tid & 63;
    const int wave_in_block = tid >> 6;
    const int gwave = blockIdx.x * 4 + wave_in_block;
    const int n0 = gwave * ROWS_PER_WAVE;

    float acc[ROWS_PER_WAVE][NEXP];
#pragma unroll
    for (int r = 0; r < ROWS_PER_WAVE; ++r)
#pragma unroll
        for (int e = 0; e < NEXP; ++e) acc[r][e] = 0.f;

    const int iters = C >> 8;  // C / (64 lanes * 4 floats)
    const float4* __restrict__ gate4 = reinterpret_cast<const float4*>(gate);
    const float4* __restrict__ hid4  = reinterpret_cast<const float4*>(hidden);
    const int C4 = C >> 2;

    for (int it = 0; it < iters; ++it) {
        const int c4 = (it << 6) + lane;  // float4 index within a row
        float4 g[NEXP];
#pragma unroll
        for (int e = 0; e < NEXP; ++e)
            g[e] = gate4[(size_t)e * C4 + c4];
#pragma unroll
        for (int r = 0; r < ROWS_PER_WAVE; ++r) {
            const float4 h = hid4[(size_t)(n0 + r) * C4 + c4];
#pragma unroll
            for (int e = 0; e < NEXP; ++e) {
                acc[r][e] = fmaf(h.x, g[e].x, acc[r][e]);
                acc[r][e] = fmaf(h.y, g[e].y, acc[r][e]);
                acc[r][e] = fmaf(h.z, g[e].z, acc[r][e]);
                acc[r][e] = fmaf(h.w, g[e].w, acc[r][e]);
            }
        }
    }

    // Butterfly reduce each of the 16 partial dots across the 64-lane wave.
#pragma unroll
    for (int r = 0; r < ROWS_PER_WAVE; ++r)
#pragma unroll
        for (int e = 0; e < NEXP; ++e) {
            float v = acc[r][e];
#pragma unroll
            for (int off = 32; off >= 1; off >>= 1)
                v += __shfl_xor(v, off, 64);
            acc[r][e] = v;
        }

    // Lanes 0..3 finish one row each (every lane holds all 16 sums).
    if (lane < ROWS_PER_WAVE) {
        const int n = n0 + lane;
        const float m = mass[n];
        float l[NEXP];
#pragma unroll
        for (int e = 0; e < NEXP; ++e) l[e] = acc[lane][e] + m * bias[e];

        reinterpret_cast<float4*>(out_logits)[n] =
            make_float4(l[0], l[1], l[2], l[3]);

        // softmax over 4
        const float mx = fmaxf(fmaxf(l[0], l[1]), fmaxf(l[2], l[3]));
        float p[NEXP];
        float s = 0.f;
#pragma unroll
        for (int e = 0; e < NEXP; ++e) { p[e] = __expf(l[e] - mx); s += p[e]; }
        const float inv = __frcp_rn(s);
#pragma unroll
        for (int e = 0; e < NEXP; ++e) p[e] *= inv;

        // top-2, ties -> lowest index (strict > while scanning ascending)
        int i0 = 0;
#pragma unroll
        for (int e = 1; e < NEXP; ++e) if (p[e] > p[i0]) i0 = e;
        int i1 = (i0 == 0) ? 1 : 0;
#pragma unroll
        for (int e = 0; e < NEXP; ++e)
            if (e != i0 && p[e] > p[i1]) i1 = e;

        out_idx[2 * n]     = (float)i0;
        out_idx[2 * n + 1] = (float)i1;
        out_w[2 * n]       = p[i0];
        out_w[2 * n + 1]   = p[i1];

#pragma unroll
        for (int e = 0; e < NEXP; ++e) atomicAdd(&lds_sum[e], p[e]);
    }
    __syncthreads();
    if (tid < NEXP) atomicAdd(&ws_sums[tid], lds_sum[tid]);
}

__global__ void physics_router_aux(const float* __restrict__ ws_sums,
                                   float* __restrict__ out_aux,
                                   float target)
{
    if (threadIdx.x == 0) {
        float a = 0.f;
#pragma unroll
        for (int e = 0; e < NEXP; ++e) {
            const float d = ws_sums[e] - target;
            a += d * d;
        }
        out_aux[0] = a * (1.f / NEXP);
    }
}

extern "C" void kernel_launch(void* const* d_in, const int* in_sizes, int n_in,
                              void* d_out, int out_size, void* d_ws, size_t ws_size,
                              hipStream_t stream) {
    const float* hidden = (const float*)d_in[0];
    const float* mass   = (const float*)d_in[1];
    const float* gate   = (const float*)d_in[2];
    const float* bias   = (const float*)d_in[3];

    const int N = in_sizes[1];            // B*T (mass element count)
    const int E = in_sizes[3];            // 4
    const int C = in_sizes[2] / E;        // 4096

    float* out = (float*)d_out;
    float* out_logits = out;                      // N*4
    float* out_idx    = out + (size_t)N * 4;      // N*2
    float* out_aux    = out + (size_t)N * 6;      // 1
    float* out_w      = out + (size_t)N * 6 + 1;  // N*2

    float* ws_sums = (float*)d_ws;
    hipMemsetAsync(ws_sums, 0, NEXP * sizeof(float), stream);

    // one wave per ROWS_PER_WAVE rows; 4 waves (256 threads) per block
    const int rows_per_block = 4 * ROWS_PER_WAVE;
    const int grid = (N + rows_per_block - 1) / rows_per_block;  // 1024
    physics_router_main<<<grid, 256, 0, stream>>>(
        hidden, mass, bias ? gate : gate, bias, out_logits, out_idx, out_w, ws_sums, C);

    const float target = (float)N / (float)E;
    physics_router_aux<<<1, 64, 0, stream>>>(ws_sums, out_aux, target);
}

// Round 4
// 369.586 us; speedup vs baseline: 1.0283x; 1.0283x over previous
//
#include <hip/hip_runtime.h>

// PhysicsRouter: N=B*T rows, C channels, E=4 experts, TOP_K=2, all fp32.
// Outputs concatenated in d_out (float):
//   [0, N*4)                logits
//   [N*4, N*4+N*2)          top_k_indices (as float)
//   [N*6, N*6+1)            aux_loss
//   [N*6+1, N*6+1+N*2)      top_k_weights
//
// R3 = R2 resubmit (broker timeout, never ran):
// RPW=2 (grid 2048 = 8 blocks/CU for TLP) + manual 2x unroll of the C-loop
// (12 float4 loads in flight before the FMA block) to cover ~900-cycle HBM
// latency. Gate (64 KB) is L2-resident; hidden streams.

#define NEXP 4
#define ROWS_PER_WAVE 2

__global__ __launch_bounds__(256, 4) void physics_router_main(
    const float* __restrict__ hidden,   // [N, C]
    const float* __restrict__ mass,     // [N]
    const float* __restrict__ gate,     // [E, C]
    const float* __restrict__ bias,     // [E]
    float* __restrict__ out_logits,     // [N*4]
    float* __restrict__ out_idx,        // [N*2] (float-encoded ints)
    float* __restrict__ out_w,          // [N*2]
    float* __restrict__ ws_sums,        // [4] global expert-importance accum
    int C)
{
    __shared__ float lds_sum[NEXP];
    const int tid = threadIdx.x;
    if (tid < NEXP) lds_sum[tid] = 0.f;
    __syncthreads();

    const int lane = tid & 63;
    const int wave_in_block = tid >> 6;
    const int gwave = blockIdx.x * 4 + wave_in_block;
    const int n0 = gwave * ROWS_PER_WAVE;

    float acc[ROWS_PER_WAVE][NEXP];
#pragma unroll
    for (int r = 0; r < ROWS_PER_WAVE; ++r)
#pragma unroll
        for (int e = 0; e < NEXP; ++e) acc[r][e] = 0.f;

    const float4* __restrict__ gate4 = reinterpret_cast<const float4*>(gate);
    const float4* __restrict__ hid4  = reinterpret_cast<const float4*>(hidden);
    const int C4 = C >> 2;                 // float4s per row (1024)
    const int steps = C >> 9;              // C / (64 lanes * 4 floats * 2 unroll) = 8

    for (int it = 0; it < steps; ++it) {
        const int c4 = (it << 7) + lane;   // base float4 index; second half at +64
        // Issue all 12 loads before any FMA so the compiler can keep them
        // in flight together (fine-grained vmcnt before each use).
        float4 g0[NEXP], g1[NEXP];
#pragma unroll
        for (int e = 0; e < NEXP; ++e) {
            g0[e] = gate4[(size_t)e * C4 + c4];
            g1[e] = gate4[(size_t)e * C4 + c4 + 64];
        }
        float4 h0[ROWS_PER_WAVE], h1[ROWS_PER_WAVE];
#pragma unroll
        for (int r = 0; r < ROWS_PER_WAVE; ++r) {
            h0[r] = hid4[(size_t)(n0 + r) * C4 + c4];
            h1[r] = hid4[(size_t)(n0 + r) * C4 + c4 + 64];
        }
#pragma unroll
        for (int r = 0; r < ROWS_PER_WAVE; ++r) {
#pragma unroll
            for (int e = 0; e < NEXP; ++e) {
                float a = acc[r][e];
                a = fmaf(h0[r].x, g0[e].x, a);
                a = fmaf(h0[r].y, g0[e].y, a);
                a = fmaf(h0[r].z, g0[e].z, a);
                a = fmaf(h0[r].w, g0[e].w, a);
                a = fmaf(h1[r].x, g1[e].x, a);
                a = fmaf(h1[r].y, g1[e].y, a);
                a = fmaf(h1[r].z, g1[e].z, a);
                a = fmaf(h1[r].w, g1[e].w, a);
                acc[r][e] = a;
            }
        }
    }

    // Butterfly reduce each of the 8 partial dots across the 64-lane wave.
#pragma unroll
    for (int r = 0; r < ROWS_PER_WAVE; ++r)
#pragma unroll
        for (int e = 0; e < NEXP; ++e) {
            float v = acc[r][e];
#pragma unroll
            for (int off = 32; off >= 1; off >>= 1)
                v += __shfl_xor(v, off, 64);
            acc[r][e] = v;
        }

    // Lanes 0..1 finish one row each (every lane holds all 8 sums).
    if (lane < ROWS_PER_WAVE) {
        const int n = n0 + lane;
        const float m = mass[n];
        float l[NEXP];
#pragma unroll
        for (int e = 0; e < NEXP; ++e) l[e] = acc[lane][e] + m * bias[e];

        reinterpret_cast<float4*>(out_logits)[n] =
            make_float4(l[0], l[1], l[2], l[3]);

        // softmax over 4
        const float mx = fmaxf(fmaxf(l[0], l[1]), fmaxf(l[2], l[3]));
        float p[NEXP];
        float s = 0.f;
#pragma unroll
        for (int e = 0; e < NEXP; ++e) { p[e] = __expf(l[e] - mx); s += p[e]; }
        const float inv = __frcp_rn(s);
#pragma unroll
        for (int e = 0; e < NEXP; ++e) p[e] *= inv;

        // top-2, ties -> lowest index
        int i0 = 0;
#pragma unroll
        for (int e = 1; e < NEXP; ++e) if (p[e] > p[i0]) i0 = e;
        int i1 = (i0 == 0) ? 1 : 0;
#pragma unroll
        for (int e = 0; e < NEXP; ++e)
            if (e != i0 && p[e] > p[i1]) i1 = e;

        out_idx[2 * n]     = (float)i0;
        out_idx[2 * n + 1] = (float)i1;
        out_w[2 * n]       = p[i0];
        out_w[2 * n + 1]   = p[i1];

#pragma unroll
        for (int e = 0; e < NEXP; ++e) atomicAdd(&lds_sum[e], p[e]);
    }
    __syncthreads();
    if (tid < NEXP) atomicAdd(&ws_sums[tid], lds_sum[tid]);
}

__global__ void physics_router_aux(const float* __restrict__ ws_sums,
                                   float* __restrict__ out_aux,
                                   float target)
{
    if (threadIdx.x == 0) {
        float a = 0.f;
#pragma unroll
        for (int e = 0; e < NEXP; ++e) {
            const float d = ws_sums[e] - target;
            a += d * d;
        }
        out_aux[0] = a * (1.f / NEXP);
    }
}

extern "C" void kernel_launch(void* const* d_in, const int* in_sizes, int n_in,
                              void* d_out, int out_size, void* d_ws, size_t ws_size,
                              hipStream_t stream) {
    const float* hidden = (const float*)d_in[0];
    const float* mass   = (const float*)d_in[1];
    const float* gate   = (const float*)d_in[2];
    const float* bias   = (const float*)d_in[3];

    const int N = in_sizes[1];            // B*T (mass element count)
    const int E = in_sizes[3];            // 4
    const int C = in_sizes[2] / E;        // 4096

    float* out = (float*)d_out;
    float* out_logits = out;                      // N*4
    float* out_idx    = out + (size_t)N * 4;      // N*2
    float* out_aux    = out + (size_t)N * 6;      // 1
    float* out_w      = out + (size_t)N * 6 + 1;  // N*2

    float* ws_sums = (float*)d_ws;
    hipMemsetAsync(ws_sums, 0, NEXP * sizeof(float), stream);

    // one wave per ROWS_PER_WAVE rows; 4 waves (256 threads) per block
    const int rows_per_block = 4 * ROWS_PER_WAVE;
    const int grid = (N + rows_per_block - 1) / rows_per_block;  // 2048
    physics_router_main<<<grid, 256, 0, stream>>>(
        hidden, mass, gate, bias, out_logits, out_idx, out_w, ws_sums, C);

    const float target = (float)N / (float)E;
    physics_router_aux<<<1, 64, 0, stream>>>(ws_sums, out_aux, target);
}